// Round 9
// baseline (232.294 us; speedup 1.0000x reference)
//
#include <hip/hip_runtime.h>
#include <hip/hip_bf16.h>

// TurboQuantMSE: x_hat = Q(x @ R^T) @ R, Q = 16-level Lloyd-Max quantizer.
// Round 9: SPLIT-K=2 on the proven R6 geometry (128x256, BK=32, 8 waves,
// 3x24KB LDS, counted vmcnt, swizzle, setprio). Grid 512 -> 2 independent
// 8-wave gangs per CU (LDS 144/160KB): cross-gang anti-phase overlap breaks
// the measured serialization (LDS-phase vs MFMA-phase lockstep = 1594cyc/tile
// serial sum). Partials: slab0 = d_out (free f32 scratch), slab1 = +32MB ws
// (runtime ws_size check; fallback = exact R6 full-K path). Merge kernels
// (quantize-merge -> Yh fp16; add-merge -> d_out) ordered by kernel boundary.

typedef __attribute__((ext_vector_type(8))) _Float16 f16x8;
typedef __attribute__((ext_vector_type(4))) float f32x4;

__device__ __forceinline__ unsigned short f2h(float f) {
    _Float16 h = (_Float16)f;
    return *reinterpret_cast<unsigned short*>(&h);
}

__device__ __forceinline__ float quant16(float yn, const float* c) {
    float v = c[0];
#pragma unroll
    for (int i = 0; i < 15; i++) {
        const float bnd = 0.5f * (c[i] + c[i + 1]);
        v = (yn > bnd) ? c[i + 1] : v;
    }
    return v;
}

// ---------------- elementwise f32 -> fp16 (x) ----------------
__global__ __launch_bounds__(256) void convert_x_kernel(
    const float* __restrict__ x, unsigned short* __restrict__ xb) {
    const int i = (blockIdx.x * 256 + threadIdx.x) * 4;
    float4 v = *reinterpret_cast<const float4*>(x + i);
    ushort4 b;
    b.x = f2h(v.x); b.y = f2h(v.y); b.z = f2h(v.z); b.w = f2h(v.w);
    *reinterpret_cast<ushort4*>(xb + i) = b;
}

// ---------------- rotation f32 -> fp16 (row-major) + fp16 transposed --------
__global__ __launch_bounds__(256) void conv_rot_kernel(
    const float* __restrict__ R, unsigned short* __restrict__ Rb,
    unsigned short* __restrict__ Rt) {
    __shared__ float t[64][65];
    const int tid = threadIdx.x;
    const int tr = blockIdx.y * 64, tc = blockIdx.x * 64;
    const int r0 = tid >> 4;
    const int c4 = (tid & 15) << 2;
#pragma unroll
    for (int i = 0; i < 4; i++) {
        const int r = r0 + i * 16;
        float4 v = *reinterpret_cast<const float4*>(
            &R[(size_t)(tr + r) * 4096 + tc + c4]);
        ushort4 b;
        b.x = f2h(v.x); b.y = f2h(v.y); b.z = f2h(v.z); b.w = f2h(v.w);
        *reinterpret_cast<ushort4*>(&Rb[(size_t)(tr + r) * 4096 + tc + c4]) = b;
        t[r][c4 + 0] = v.x; t[r][c4 + 1] = v.y;
        t[r][c4 + 2] = v.z; t[r][c4 + 3] = v.w;
    }
    __syncthreads();
#pragma unroll
    for (int i = 0; i < 16; i++) {
        const int idx = tid + 256 * i;
        const int rr = idx >> 6;
        const int cc = idx & 63;
        Rt[(size_t)(tc + rr) * 4096 + tr + cc] = f2h(t[cc][rr]);
    }
}

// ---------------- pipelined NT GEMM -----------------------------------------
// C[2048,4096] = A[2048,K] * Bt[4096,K]^T, fp16 in, f32 accum.
// BM=128 BN=256 BK=32, 8 waves (2M x 4N), per-wave 64x64 (4x4 frags).
// MODE 0: full-K, quantize epilogue -> fp16 Yh.     (grid 256, NTK=128)
// MODE 1: full-K, f32 epilogue -> out.              (grid 256, NTK=128)
// MODE 2: half-K (wgid&1 picks K-half), f32 partial -> slab0/slab1.
//         (grid 512, NTK=64)
constexpr int GK = 4096;
constexpr int BM = 128, BN = 256, BK = 32;
constexpr int A_LDS = BM * BK * 2;          // 8192
constexpr int BUF = (BM + BN) * BK * 2;     // 24576
constexpr int LDS_DYN = 3 * BUF;            // 73728

template <int MODE, int NTK>
__global__ __launch_bounds__(512, 4) void gemm_nt_kernel(
    const unsigned short* __restrict__ A, const unsigned short* __restrict__ Bt,
    void* __restrict__ Out0, float* __restrict__ Slab1,
    const float* __restrict__ cb16) {
    extern __shared__ char smem[];
    const int tid = threadIdx.x;
    const int lane = tid & 63;
    const int w = tid >> 6;        // 0..7
    const int wm = w >> 2;         // 0..1
    const int wn = w & 3;          // 0..3

    // XCD-aware bijective swizzle (grid%8==0)
    const int bid = blockIdx.x;
    const int nwg = gridDim.x;
    const int wgid = (bid & 7) * (nwg >> 3) + (bid >> 3);
    int tile, kb;
    if constexpr (MODE == 2) {
        tile = wgid >> 1;
        kb = (wgid & 1) * (GK / 2);
    } else {
        tile = wgid;
        kb = 0;
    }
    const int tn = tile & 15;      // N/BN = 16
    const int tm = tile >> 4;      // M/BM = 16

    f32x4 acc[4][4];
#pragma unroll
    for (int m = 0; m < 4; m++)
#pragma unroll
        for (int n = 0; n < 4; n++) acc[m][n] = (f32x4){0.f, 0.f, 0.f, 0.f};

    // ---- staging: 3 chunks of 8KB (128 rows x 64B). row=tid>>2, slot=tid&3;
    // global col pre-swizzled (slot ^= (row>>1)&3); linear LDS dst.
    const int srow = tid >> 2;                                  // 0..127
    const int scol = (((tid & 3) ^ ((srow >> 1) & 3)) << 3);    // elements
    const unsigned short* ApS = A + (size_t)(tm * BM + srow) * GK + kb + scol;
    const unsigned short* BpS0 = Bt + (size_t)(tn * BN + srow) * GK + kb + scol;
    const unsigned short* BpS1 = BpS0 + (size_t)128 * GK;
    const int wbase = (w << 10);                                // w*1024 B

#define STAGE(dstbase)                                                         \
    {                                                                          \
        __builtin_amdgcn_global_load_lds(                                      \
            (const __attribute__((address_space(1))) void*)ApS,                \
            (__attribute__((address_space(3))) void*)(smem + (dstbase) + wbase), 16, 0, 0); \
        __builtin_amdgcn_global_load_lds(                                      \
            (const __attribute__((address_space(1))) void*)BpS0,               \
            (__attribute__((address_space(3))) void*)(smem + (dstbase) + A_LDS + wbase), 16, 0, 0); \
        __builtin_amdgcn_global_load_lds(                                      \
            (const __attribute__((address_space(1))) void*)BpS1,               \
            (__attribute__((address_space(3))) void*)(smem + (dstbase) + A_LDS + 8192 + wbase), 16, 0, 0); \
        ApS += BK; BpS0 += BK; BpS1 += BK;                                     \
    }

    // ---- fragment read addressing (swizzled): byte = row*64 + swslot*16 ----
    const int sw = (((lane >> 4) ^ (((lane & 15) >> 1) & 3)) << 4);
    const int arow = (wm * 64 + (lane & 15)) * 64;              // A row byte
    const int brow = A_LDS + (wn * 64 + (lane & 15)) * 64;      // B row byte

#define LDA(m) (*reinterpret_cast<const f16x8*>(smem + lb + arow + (m) * 1024 + sw))
#define LDB(n) (*reinterpret_cast<const f16x8*>(smem + lb + brow + (n) * 1024 + sw))
#define MFMA_ROW(aR, r)                                                          \
    acc[r][0] = __builtin_amdgcn_mfma_f32_16x16x32_f16(aR, b0, acc[r][0], 0, 0, 0); \
    acc[r][1] = __builtin_amdgcn_mfma_f32_16x16x32_f16(aR, b1, acc[r][1], 0, 0, 0); \
    acc[r][2] = __builtin_amdgcn_mfma_f32_16x16x32_f16(aR, b2, acc[r][2], 0, 0, 0); \
    acc[r][3] = __builtin_amdgcn_mfma_f32_16x16x32_f16(aR, b3, acc[r][3], 0, 0, 0);

    // ---- prologue: stage tile0 -> buf0, tile1 -> buf1; wait own tile0 ----
    STAGE(0)
    STAGE(BUF)
    asm volatile("s_waitcnt vmcnt(3)" ::: "memory");
    __builtin_amdgcn_s_barrier();
    __builtin_amdgcn_sched_barrier(0);

    int lb = 0;            // buffer holding tile t
    int wb = 2 * BUF;      // buffer receiving tile t+2
    for (int t = 0; t < NTK; ++t) {
        f16x8 a0, a1, a2, a3, b0, b1, b2, b3;
        a0 = LDA(0); a1 = LDA(1); a2 = LDA(2); a3 = LDA(3);
        b0 = LDB(0); b1 = LDB(1); b2 = LDB(2); b3 = LDB(3);
        if (t + 2 < NTK) STAGE(wb)
        asm volatile("s_waitcnt lgkmcnt(0)" ::: "memory");
        __builtin_amdgcn_sched_barrier(0);
        __builtin_amdgcn_s_setprio(1);
        MFMA_ROW(a0, 0) MFMA_ROW(a1, 1) MFMA_ROW(a2, 2) MFMA_ROW(a3, 3)
        __builtin_amdgcn_s_setprio(0);
        if (t + 1 < NTK) {
            if (t + 2 < NTK) {
                asm volatile("s_waitcnt vmcnt(3)" ::: "memory");
            } else {
                asm volatile("s_waitcnt vmcnt(0)" ::: "memory");
            }
            __builtin_amdgcn_s_barrier();
            __builtin_amdgcn_sched_barrier(0);
            lb = (lb == 2 * BUF) ? 0 : lb + BUF;
            wb = (wb == 2 * BUF) ? 0 : wb + BUF;
        }
    }
#undef LDA
#undef LDB
#undef MFMA_ROW
#undef STAGE

    // ---- epilogue: C/D layout col=lane&15, row=(lane>>4)*4+j ----
    const int crow0 = tm * BM + wm * 64 + ((lane >> 4) << 2);
    const int ccol0 = tn * BN + wn * 64 + (lane & 15);
    if constexpr (MODE == 0) {
        float c[16];
#pragma unroll
        for (int i = 0; i < 16; i++) c[i] = cb16[i];
        unsigned short* O = (unsigned short*)Out0;
#pragma unroll
        for (int m = 0; m < 4; m++)
#pragma unroll
            for (int n = 0; n < 4; n++)
#pragma unroll
                for (int j = 0; j < 4; j++)
                    O[(size_t)(crow0 + m * 16 + j) * 4096 + ccol0 + n * 16] =
                        f2h(quant16(acc[m][n][j] * 64.0f, c) * 0.015625f);
    } else if constexpr (MODE == 1) {
        float* O = (float*)Out0;
#pragma unroll
        for (int m = 0; m < 4; m++)
#pragma unroll
            for (int n = 0; n < 4; n++)
#pragma unroll
                for (int j = 0; j < 4; j++)
                    O[(size_t)(crow0 + m * 16 + j) * 4096 + ccol0 + n * 16] =
                        acc[m][n][j];
    } else {
        float* P = (wgid & 1) ? Slab1 : (float*)Out0;
#pragma unroll
        for (int m = 0; m < 4; m++)
#pragma unroll
            for (int n = 0; n < 4; n++)
#pragma unroll
                for (int j = 0; j < 4; j++)
                    P[(size_t)(crow0 + m * 16 + j) * 4096 + ccol0 + n * 16] =
                        acc[m][n][j];
    }
}

// ---------------- split-K merge kernels -------------------------------------
__global__ __launch_bounds__(256) void merge_quant_kernel(
    const float* __restrict__ p0, const float* __restrict__ p1,
    unsigned short* __restrict__ yh, const float* __restrict__ cb16) {
    float c[16];
#pragma unroll
    for (int i = 0; i < 16; i++) c[i] = cb16[i];
    const int i = (blockIdx.x * 256 + threadIdx.x) * 4;
    float4 a = *reinterpret_cast<const float4*>(p0 + i);
    float4 b = *reinterpret_cast<const float4*>(p1 + i);
    ushort4 o;
    o.x = f2h(quant16((a.x + b.x) * 64.0f, c) * 0.015625f);
    o.y = f2h(quant16((a.y + b.y) * 64.0f, c) * 0.015625f);
    o.z = f2h(quant16((a.z + b.z) * 64.0f, c) * 0.015625f);
    o.w = f2h(quant16((a.w + b.w) * 64.0f, c) * 0.015625f);
    *reinterpret_cast<ushort4*>(yh + i) = o;
}

__global__ __launch_bounds__(256) void merge_add_kernel(
    float* __restrict__ o, const float* __restrict__ p1) {
    const int i = (blockIdx.x * 256 + threadIdx.x) * 4;
    float4 a = *reinterpret_cast<const float4*>(o + i);
    float4 b = *reinterpret_cast<const float4*>(p1 + i);
    a.x += b.x; a.y += b.y; a.z += b.z; a.w += b.w;
    *reinterpret_cast<float4*>(o + i) = a;
}

extern "C" void kernel_launch(void* const* d_in, const int* in_sizes, int n_in,
                              void* d_out, int out_size, void* d_ws,
                              size_t ws_size, hipStream_t stream) {
    const float* x = (const float*)d_in[0];
    const float* rot = (const float*)d_in[1];
    const float* cb = (const float*)d_in[2];
    float* out = (float*)d_out;

    // ws layout (bytes): Xh 16M | Rh 32M | Rt 32M | Yh 16M | [slab1 32M]
    unsigned short* Xh = (unsigned short*)d_ws;
    unsigned short* Rh = Xh + (size_t)2048 * 4096;
    unsigned short* Rt = Rh + (size_t)4096 * 4096;
    unsigned short* Yh = Rt + (size_t)4096 * 4096;
    float* slab1 = (float*)(Yh + (size_t)2048 * 4096);
    const size_t need = (size_t)(16 + 32 + 32 + 16 + 32) * 1024 * 1024;
    const bool splitk = ws_size >= need;

    (void)hipFuncSetAttribute(
        reinterpret_cast<const void*>(&gemm_nt_kernel<0, 128>),
        hipFuncAttributeMaxDynamicSharedMemorySize, LDS_DYN);
    (void)hipFuncSetAttribute(
        reinterpret_cast<const void*>(&gemm_nt_kernel<1, 128>),
        hipFuncAttributeMaxDynamicSharedMemorySize, LDS_DYN);
    (void)hipFuncSetAttribute(
        reinterpret_cast<const void*>(&gemm_nt_kernel<2, 64>),
        hipFuncAttributeMaxDynamicSharedMemorySize, LDS_DYN);

    convert_x_kernel<<<8192, 256, 0, stream>>>(x, Xh);
    conv_rot_kernel<<<dim3(64, 64), 256, 0, stream>>>(rot, Rh, Rt);

    if (splitk) {
        // GEMM1 split: partials -> {d_out, slab1}; merge+quantize -> Yh
        gemm_nt_kernel<2, 64><<<512, 512, LDS_DYN, stream>>>(
            Xh, Rh, (void*)out, slab1, cb);
        merge_quant_kernel<<<8192, 256, 0, stream>>>(out, slab1, Yh, cb);
        // GEMM2 split: partials -> {d_out, slab1}; merge -> d_out
        gemm_nt_kernel<2, 64><<<512, 512, LDS_DYN, stream>>>(
            Yh, Rt, (void*)out, slab1, nullptr);
        merge_add_kernel<<<8192, 256, 0, stream>>>(out, slab1);
    } else {
        gemm_nt_kernel<0, 128><<<256, 512, LDS_DYN, stream>>>(
            Xh, Rh, (void*)Yh, nullptr, cb);
        gemm_nt_kernel<1, 128><<<256, 512, LDS_DYN, stream>>>(
            Yh, Rt, (void*)out, nullptr, nullptr);
    }
}

// Round 10
// 164.063 us; speedup vs baseline: 1.4159x; 1.4159x over previous
//
#include <hip/hip_runtime.h>
#include <hip/hip_bf16.h>

// TurboQuantMSE: x_hat = Q(x @ R^T) @ R, Q = 16-level Lloyd-Max quantizer.
// Round 10: K-PAIRED 64x128 WAVE TILES. 8 waves = 4 positions (2M x 2N over
// BM=128/BN=256) x 2 K-half waves (BK=64 split). Wave tile 64x128 has
// FLOP/LDS-byte 42.7 vs 64x64's 32 -> 25% fewer ds_reads, the measured top
// consumer (LDS port ~1060cyc/tile vs MFMA 155). Acc pairs merge via LDS
// after the K-loop. Keeps proven pieces: grid 256 (fetch 139MB), 3-buffer
// counted vmcnt(6), XOR swizzle (slot^=row&7 on 128B rows), setprio.

typedef __attribute__((ext_vector_type(8))) _Float16 f16x8;
typedef __attribute__((ext_vector_type(4))) float f32x4;

__device__ __forceinline__ unsigned short f2h(float f) {
    _Float16 h = (_Float16)f;
    return *reinterpret_cast<unsigned short*>(&h);
}

__device__ __forceinline__ float quant16(float yn, const float* c) {
    float v = c[0];
#pragma unroll
    for (int i = 0; i < 15; i++) {
        const float bnd = 0.5f * (c[i] + c[i + 1]);
        v = (yn > bnd) ? c[i + 1] : v;
    }
    return v;
}

// ---------------- elementwise f32 -> fp16 (x) ----------------
__global__ __launch_bounds__(256) void convert_x_kernel(
    const float* __restrict__ x, unsigned short* __restrict__ xb) {
    const int i = (blockIdx.x * 256 + threadIdx.x) * 4;
    float4 v = *reinterpret_cast<const float4*>(x + i);
    ushort4 b;
    b.x = f2h(v.x); b.y = f2h(v.y); b.z = f2h(v.z); b.w = f2h(v.w);
    *reinterpret_cast<ushort4*>(xb + i) = b;
}

// ---------------- rotation f32 -> fp16 (row-major) + fp16 transposed --------
__global__ __launch_bounds__(256) void conv_rot_kernel(
    const float* __restrict__ R, unsigned short* __restrict__ Rb,
    unsigned short* __restrict__ Rt) {
    __shared__ float t[64][65];
    const int tid = threadIdx.x;
    const int tr = blockIdx.y * 64, tc = blockIdx.x * 64;
    const int r0 = tid >> 4;
    const int c4 = (tid & 15) << 2;
#pragma unroll
    for (int i = 0; i < 4; i++) {
        const int r = r0 + i * 16;
        float4 v = *reinterpret_cast<const float4*>(
            &R[(size_t)(tr + r) * 4096 + tc + c4]);
        ushort4 b;
        b.x = f2h(v.x); b.y = f2h(v.y); b.z = f2h(v.z); b.w = f2h(v.w);
        *reinterpret_cast<ushort4*>(&Rb[(size_t)(tr + r) * 4096 + tc + c4]) = b;
        t[r][c4 + 0] = v.x; t[r][c4 + 1] = v.y;
        t[r][c4 + 2] = v.z; t[r][c4 + 3] = v.w;
    }
    __syncthreads();
#pragma unroll
    for (int i = 0; i < 16; i++) {
        const int idx = tid + 256 * i;
        const int rr = idx >> 6;
        const int cc = idx & 63;
        Rt[(size_t)(tc + rr) * 4096 + tr + cc] = f2h(t[cc][rr]);
    }
}

// ---------------- K-paired NT GEMM ------------------------------------------
// C[2048,4096] = A[2048,K] * Bt[4096,K]^T, fp16 in, f32 accum.
// BM=128 BN=256 BK=64. 8 waves: pos=w&3 (wm=pos>>1, wn=pos&1) owns a 64x128
// output tile; kp=w>>2 picks the BK/2 K-half. acc[4][8] per wave; pair sums
// merged via LDS in the epilogue. LDS buffer = A 16KB + B 32KB = 48KB x3.
// 6 staging chunks/tile (A:2, B:4), 2-tile lead, boundary vmcnt(6).
constexpr int GK = 4096;
constexpr int BM = 128, BN = 256, BK = 64;
constexpr int NT = GK / BK;                 // 64
constexpr int A_LDS = BM * BK * 2;          // 16384
constexpr int BUF = (BM + BN) * BK * 2;     // 49152
constexpr int LDS_DYN = 3 * BUF;            // 147456

template <bool QUANT>
__global__ __launch_bounds__(512, 2) void gemm_nt_kernel(
    const unsigned short* __restrict__ A, const unsigned short* __restrict__ Bt,
    void* __restrict__ Cout, const float* __restrict__ cb16) {
    extern __shared__ char smem[];
    const int tid = threadIdx.x;
    const int lane = tid & 63;
    const int w = tid >> 6;        // 0..7
    const int pos = w & 3;
    const int wm = pos >> 1;       // 0..1 (64-row block)
    const int wn = pos & 1;        // 0..1 (128-col block)
    const int kp = w >> 2;         // 0..1 (K-half of BK)

    // XCD-aware bijective swizzle (256 blocks, 256%8==0)
    const int bid = blockIdx.x;
    const int wgid = (bid & 7) * 32 + (bid >> 3);
    const int tn = wgid & 15;      // N/BN = 16
    const int tm = wgid >> 4;      // M/BM = 16

    f32x4 acc[4][8];
#pragma unroll
    for (int m = 0; m < 4; m++)
#pragma unroll
        for (int n = 0; n < 8; n++) acc[m][n] = (f32x4){0.f, 0.f, 0.f, 0.f};

    // ---- staging: 6 chunks of 8KB (64 rows x 128B). row=tid>>3, slot=tid&7;
    // global col pre-swizzled (slot ^= row&7); linear LDS dst (wave-uniform
    // base + HW lane*16).
    const int srow = tid >> 3;                                  // 0..63
    const int scol = (((tid & 7) ^ (srow & 7)) << 3);           // elements
    const unsigned short* ApS0 = A + (size_t)(tm * BM + srow) * GK + scol;
    const unsigned short* ApS1 = ApS0 + (size_t)64 * GK;
    const unsigned short* BpS0 = Bt + (size_t)(tn * BN + srow) * GK + scol;
    const unsigned short* BpS1 = BpS0 + (size_t)64 * GK;
    const unsigned short* BpS2 = BpS0 + (size_t)128 * GK;
    const unsigned short* BpS3 = BpS0 + (size_t)192 * GK;
    const int wbase = (w << 10);                                // w*1024 B

#define GLL(src, off)                                                          \
    __builtin_amdgcn_global_load_lds(                                          \
        (const __attribute__((address_space(1))) void*)(src),                  \
        (__attribute__((address_space(3))) void*)(smem + (off) + wbase), 16, 0, 0);
#define STAGE(dstbase)                                                         \
    {                                                                          \
        GLL(ApS0, (dstbase) + 0)                                               \
        GLL(ApS1, (dstbase) + 8192)                                            \
        GLL(BpS0, (dstbase) + 16384)                                           \
        GLL(BpS1, (dstbase) + 24576)                                           \
        GLL(BpS2, (dstbase) + 32768)                                           \
        GLL(BpS3, (dstbase) + 40960)                                           \
        ApS0 += BK; ApS1 += BK; BpS0 += BK; BpS1 += BK; BpS2 += BK; BpS3 += BK;\
    }

    // ---- fragment read addressing (swizzled): byte = row*128 + slot'*16,
    // slot' = (kp*4 + (lane>>4)) ^ (row&7). Banks: 2-way max (free).
    const int frow = lane & 15;
    const int sw = (((kp * 4 + (lane >> 4)) ^ (frow & 7)) << 4);
    const int arow = (wm * 64 + frow) * 128;              // A row byte
    const int brow = (wn * 128 + frow) * 128;             // B row byte (in B rgn)

#define LDA(m) (*reinterpret_cast<const f16x8*>(smem + lb + arow + (m) * 2048 + sw))
#define LDB(n) (*reinterpret_cast<const f16x8*>(smem + lb + A_LDS + brow + (n) * 2048 + sw))
#define MFMA_ROW(aR, r)                                                          \
    acc[r][0] = __builtin_amdgcn_mfma_f32_16x16x32_f16(aR, b0, acc[r][0], 0, 0, 0); \
    acc[r][1] = __builtin_amdgcn_mfma_f32_16x16x32_f16(aR, b1, acc[r][1], 0, 0, 0); \
    acc[r][2] = __builtin_amdgcn_mfma_f32_16x16x32_f16(aR, b2, acc[r][2], 0, 0, 0); \
    acc[r][3] = __builtin_amdgcn_mfma_f32_16x16x32_f16(aR, b3, acc[r][3], 0, 0, 0); \
    acc[r][4] = __builtin_amdgcn_mfma_f32_16x16x32_f16(aR, b4, acc[r][4], 0, 0, 0); \
    acc[r][5] = __builtin_amdgcn_mfma_f32_16x16x32_f16(aR, b5, acc[r][5], 0, 0, 0); \
    acc[r][6] = __builtin_amdgcn_mfma_f32_16x16x32_f16(aR, b6, acc[r][6], 0, 0, 0); \
    acc[r][7] = __builtin_amdgcn_mfma_f32_16x16x32_f16(aR, b7, acc[r][7], 0, 0, 0);

    // ---- prologue: stage tile0 -> buf0, tile1 -> buf1; wait own tile0 ----
    STAGE(0)
    STAGE(BUF)
    asm volatile("s_waitcnt vmcnt(6)" ::: "memory");
    __builtin_amdgcn_s_barrier();
    __builtin_amdgcn_sched_barrier(0);

    int lb = 0;            // buffer holding tile t
    int wb = 2 * BUF;      // buffer receiving tile t+2
    for (int t = 0; t < NT; ++t) {
        f16x8 a0, a1, a2, a3, b0, b1, b2, b3, b4, b5, b6, b7;
        a0 = LDA(0); a1 = LDA(1); a2 = LDA(2); a3 = LDA(3);
        b0 = LDB(0); b1 = LDB(1); b2 = LDB(2); b3 = LDB(3);
        b4 = LDB(4); b5 = LDB(5); b6 = LDB(6); b7 = LDB(7);
        if (t + 2 < NT) STAGE(wb)
        asm volatile("s_waitcnt lgkmcnt(0)" ::: "memory");
        __builtin_amdgcn_sched_barrier(0);
        __builtin_amdgcn_s_setprio(1);
        MFMA_ROW(a0, 0) MFMA_ROW(a1, 1) MFMA_ROW(a2, 2) MFMA_ROW(a3, 3)
        __builtin_amdgcn_s_setprio(0);
        if (t + 1 < NT) {
            if (t + 2 < NT) {
                asm volatile("s_waitcnt vmcnt(6)" ::: "memory");
            } else {
                asm volatile("s_waitcnt vmcnt(0)" ::: "memory");
            }
            __builtin_amdgcn_s_barrier();
            __builtin_amdgcn_sched_barrier(0);
            lb = (lb == 2 * BUF) ? 0 : lb + BUF;
            wb = (wb == 2 * BUF) ? 0 : wb + BUF;
        }
    }
#undef LDA
#undef LDB
#undef MFMA_ROW
#undef STAGE
#undef GLL

    // ---- pair merge: kp=1 wave dumps acc to LDS; kp=0 adds and writes C ----
    __syncthreads();   // all K-loop LDS reads done before overwrite
    if (kp == 1) {
#pragma unroll
        for (int m = 0; m < 4; m++)
#pragma unroll
            for (int n = 0; n < 8; n++)
                *reinterpret_cast<f32x4*>(
                    smem + pos * 32768 + (m * 8 + n) * 1024 + lane * 16) =
                    acc[m][n];
    }
    __syncthreads();
    if (kp == 1) return;

    const int g = lane >> 4;
    const int crow0 = tm * BM + wm * 64 + (g << 2);
    const int ccol0 = tn * BN + wn * 128 + frow;
    if constexpr (QUANT) {
        float c[16];
#pragma unroll
        for (int i = 0; i < 16; i++) c[i] = cb16[i];
        unsigned short* O = (unsigned short*)Cout;
#pragma unroll
        for (int m = 0; m < 4; m++)
#pragma unroll
            for (int n = 0; n < 8; n++) {
                f32x4 other = *reinterpret_cast<const f32x4*>(
                    smem + pos * 32768 + (m * 8 + n) * 1024 + lane * 16);
#pragma unroll
                for (int j = 0; j < 4; j++) {
                    const float s = acc[m][n][j] + other[j];
                    O[(size_t)(crow0 + m * 16 + j) * 4096 + ccol0 + n * 16] =
                        f2h(quant16(s * 64.0f, c) * 0.015625f);
                }
            }
    } else {
        float* O = (float*)Cout;
#pragma unroll
        for (int m = 0; m < 4; m++)
#pragma unroll
            for (int n = 0; n < 8; n++) {
                f32x4 other = *reinterpret_cast<const f32x4*>(
                    smem + pos * 32768 + (m * 8 + n) * 1024 + lane * 16);
#pragma unroll
                for (int j = 0; j < 4; j++)
                    O[(size_t)(crow0 + m * 16 + j) * 4096 + ccol0 + n * 16] =
                        acc[m][n][j] + other[j];
            }
    }
}

extern "C" void kernel_launch(void* const* d_in, const int* in_sizes, int n_in,
                              void* d_out, int out_size, void* d_ws,
                              size_t ws_size, hipStream_t stream) {
    const float* x = (const float*)d_in[0];
    const float* rot = (const float*)d_in[1];
    const float* cb = (const float*)d_in[2];
    float* out = (float*)d_out;

    unsigned short* Xh = (unsigned short*)d_ws;
    unsigned short* Rh = Xh + (size_t)2048 * 4096;
    unsigned short* Rt = Rh + (size_t)4096 * 4096;
    unsigned short* Yh = Rt + (size_t)4096 * 4096;

    (void)hipFuncSetAttribute(
        reinterpret_cast<const void*>(&gemm_nt_kernel<true>),
        hipFuncAttributeMaxDynamicSharedMemorySize, LDS_DYN);
    (void)hipFuncSetAttribute(
        reinterpret_cast<const void*>(&gemm_nt_kernel<false>),
        hipFuncAttributeMaxDynamicSharedMemorySize, LDS_DYN);

    convert_x_kernel<<<8192, 256, 0, stream>>>(x, Xh);
    conv_rot_kernel<<<dim3(64, 64), 256, 0, stream>>>(rot, Rh, Rt);
    // y = x @ R^T : NT GEMM, Bt = Rh
    gemm_nt_kernel<true><<<256, 512, LDS_DYN, stream>>>(Xh, Rh, (void*)Yh, cb);
    // x_hat = y_hat @ R = y_hat @ (R^T)^T : NT GEMM, Bt = Rt
    gemm_nt_kernel<false><<<256, 512, LDS_DYN, stream>>>(Yh, Rt, (void*)out, nullptr);
}